// Round 5
// baseline (570.619 us; speedup 1.0000x reference)
//
#include <hip/hip_runtime.h>
#include <math.h>

#define N_NODES   100000
#define N_EDGES   1000000
#define N_GRAPHS  256
#define NUM_TYPES 200
#define EMB       64
#define HID       32

#define BSHIFT    8
#define BSTRIDE   256                                   // nodes per bucket
#define NBUCK     ((N_NODES + BSTRIDE - 1) / BSTRIDE)   // 391
#define EPB       4096                                  // edges per bin block
#define NBINBLK   ((N_EDGES + EPB - 1) / EPB)           // 245

// ---------------- binning (CSR replacement) ----------------

// per-block bucket histogram -> counts[k*NBUCK + b]
__global__ __launch_bounds__(256) void k_binA(const int* __restrict__ dst,
                                              int* __restrict__ counts) {
    __shared__ int cnt[NBUCK];
    int tid = threadIdx.x, k = blockIdx.x;
    for (int b = tid; b < NBUCK; b += 256) cnt[b] = 0;
    __syncthreads();
    int base = k * EPB;
    int n = min(EPB, N_EDGES - base);
    for (int t = tid; t < n; t += 256) atomicAdd(&cnt[dst[base + t] >> BSHIFT], 1);
    __syncthreads();
    for (int b = tid; b < NBUCK; b += 256) counts[k * NBUCK + b] = cnt[b];
}

// one block: absolute offsets offs[k*NBUCK+b] and bucket bases bbase[0..NBUCK]
__global__ __launch_bounds__(512) void k_binScan(const int* __restrict__ counts,
                                                 int* __restrict__ offs,
                                                 int* __restrict__ bbase) {
    __shared__ int sA[512], sB[512];
    int tid = threadIdx.x;
    int total = 0;
    if (tid < NBUCK)
        for (int k = 0; k < NBINBLK; ++k) total += counts[k * NBUCK + tid];
    sA[tid] = (tid < NBUCK) ? total : 0;
    __syncthreads();
    int* in = sA; int* out = sB;
    for (int off = 1; off < 512; off <<= 1) {
        out[tid] = in[tid] + (tid >= off ? in[tid - off] : 0);
        __syncthreads();
        int* tmp = in; in = out; out = tmp;
    }
    int excl = in[tid] - ((tid < NBUCK) ? total : 0);
    if (tid < NBUCK) {
        bbase[tid] = excl;
        int run = excl;
        for (int k = 0; k < NBINBLK; ++k) {
            offs[k * NBUCK + tid] = run;
            run += counts[k * NBUCK + tid];
        }
    }
    if (tid == 0) bbase[NBUCK] = N_EDGES;
}

// LDS counting-sort by bucket within each block; coalesced write of (src,dst)
// pairs into bucket-grouped global order.
__global__ __launch_bounds__(256) void k_binB(const int* __restrict__ src,
                                              const int* __restrict__ dst,
                                              const int* __restrict__ offs,
                                              int2* __restrict__ binned) {
    __shared__ int srcl[EPB];
    __shared__ int dstl[EPB];
    __shared__ unsigned short rank16[EPB];
    __shared__ unsigned short perm[EPB];
    __shared__ int cnt[NBUCK];
    __shared__ int loc[NBUCK];
    __shared__ int offsL[NBUCK];
    __shared__ int sA[512], sB[512];
    int tid = threadIdx.x, k = blockIdx.x;
    int base = k * EPB;
    int n = min(EPB, N_EDGES - base);
    for (int b = tid; b < NBUCK; b += 256) { cnt[b] = 0; offsL[b] = offs[k * NBUCK + b]; }
    __syncthreads();
    for (int t = tid; t < n; t += 256) {
        int s = src[base + t], d = dst[base + t];
        srcl[t] = s; dstl[t] = d;
        rank16[t] = (unsigned short)atomicAdd(&cnt[d >> BSHIFT], 1);
    }
    __syncthreads();
    for (int t = tid; t < 512; t += 256) sA[t] = (t < NBUCK) ? cnt[t] : 0;
    __syncthreads();
    int* in = sA; int* out = sB;
    for (int off = 1; off < 512; off <<= 1) {
        for (int t = tid; t < 512; t += 256)
            out[t] = in[t] + (t >= off ? in[t - off] : 0);
        __syncthreads();
        int* tmp = in; in = out; out = tmp;
    }
    for (int b = tid; b < NBUCK; b += 256) loc[b] = in[b] - cnt[b];
    __syncthreads();
    for (int t = tid; t < n; t += 256) {
        int b = dstl[t] >> BSHIFT;
        perm[loc[b] + rank16[t]] = (unsigned short)t;
    }
    __syncthreads();
    for (int t = tid; t < n; t += 256) {
        int e = perm[t];
        int d = dstl[e], b = d >> BSHIFT;
        int gpos = offsL[b] + (t - loc[b]);
        binned[gpos] = make_int2(srcl[e], d);
    }
}

// per-bucket degree count -> dinv
__global__ __launch_bounds__(256) void k_deg(const int2* __restrict__ binned,
                                             const int* __restrict__ bbase,
                                             float* __restrict__ dinv) {
    __shared__ int cnt[BSTRIDE];
    int tid = threadIdx.x, b = blockIdx.x;
    cnt[tid] = 0;
    __syncthreads();
    int e0 = bbase[b], e1 = bbase[b + 1];
    for (int t = e0 + tid; t < e1; t += 256) atomicAdd(&cnt[binned[t].y & (BSTRIDE - 1)], 1);
    __syncthreads();
    int i = b * BSTRIDE + tid;
    if (i < N_NODES) dinv[i] = rsqrtf((float)cnt[tid] + 1.0f);
}

// ---------------- feature pipeline ----------------

// table[t][j] = sum_k emb[t][k] * W1[k][j]   (200 x 32)
__global__ void k_table(const float* __restrict__ emb, const float* __restrict__ W1,
                        float* __restrict__ table) {
    int i = blockIdx.x * blockDim.x + threadIdx.x;
    if (i >= NUM_TYPES * HID) return;
    int t = i / HID, j = i % HID;
    float s = 0.f;
    for (int k = 0; k < EMB; ++k) s = fmaf(emb[t * EMB + k], W1[k * HID + j], s);
    table[i] = s;
}

// layer1 gather (edge-parallel, LDS acc) + relu + W2 GEMM epilogue -> Y2
__global__ __launch_bounds__(512) void k_gather1(
        const int2* __restrict__ binned, const int* __restrict__ bbase,
        const int* __restrict__ ids, const float* __restrict__ dinv,
        const float* __restrict__ table, const float* __restrict__ W2,
        const float* __restrict__ b1, float4* __restrict__ Y2) {
    __shared__ float tabT[HID][NUM_TYPES + 8];     // [feature][type]
    __shared__ float acc[HID][BSTRIDE + 1];        // [feature][node-local]
    __shared__ float w2s[HID * HID];
    __shared__ float b1s[HID];
    int tid = threadIdx.x, b = blockIdx.x;
    for (int t = tid; t < NUM_TYPES * HID; t += 512) {
        int id = t >> 5, c = t & 31;
        tabT[c][id] = table[t];
    }
    for (int t = tid; t < HID * HID; t += 512) w2s[t] = W2[t];
    if (tid < HID) b1s[tid] = b1[tid];
    for (int t = tid; t < HID * (BSTRIDE + 1); t += 512) ((float*)acc)[t] = 0.f;
    __syncthreads();

    int e0 = bbase[b], e1 = bbase[b + 1];
    int p = tid & 7, g = tid >> 3;                 // 64 edges in flight
    for (int t = e0 + g; t < e1; t += 64) {
        int2 pr = binned[t];
        int s = pr.x, dl = pr.y & (BSTRIDE - 1);
        float ds = dinv[s];
        int id = ids[s];
#pragma unroll
        for (int cc = 0; cc < 4; ++cc) {
            float v = tabT[4 * p + cc][id] * ds;
            atomicAdd(&acc[4 * p + cc][dl], v);
        }
    }
    __syncthreads();

    if (tid < BSTRIDE) {
        int i = b * BSTRIDE + tid;
        if (i < N_NODES) {
            float di = dinv[i];
            int id = ids[i];
            float h[HID];
#pragma unroll
            for (int c = 0; c < HID; ++c) {
                float tot = acc[c][tid] + tabT[c][id] * di;   // + self term
                h[c] = fmaxf(fmaf(di, tot, b1s[c]), 0.f);
            }
            float o[HID];
#pragma unroll
            for (int j = 0; j < HID; ++j) o[j] = 0.f;
            for (int c = 0; c < HID; ++c) {
                float hc = h[c];
#pragma unroll
                for (int j = 0; j < HID; ++j) o[j] = fmaf(hc, w2s[c * HID + j], o[j]);
            }
#pragma unroll
            for (int q = 0; q < 8; ++q) {
                float4 v;
                v.x = o[4 * q + 0] * di; v.y = o[4 * q + 1] * di;
                v.z = o[4 * q + 2] * di; v.w = o[4 * q + 3] * di;
                Y2[(size_t)i * 8 + q] = v;
            }
        }
    }
}

// layer2 gather (edge-parallel, LDS acc) + relu + fused per-bucket pooling
__global__ __launch_bounds__(512) void k_gather2(
        const int2* __restrict__ binned, const int* __restrict__ bbase,
        const float4* __restrict__ Y2, const float* __restrict__ dinv,
        const float* __restrict__ b2, const int* __restrict__ batch,
        float* __restrict__ pooled) {
    __shared__ float acc[HID][BSTRIDE + 1];
    __shared__ float pool[16][HID];
    __shared__ float b2s[HID];
    int tid = threadIdx.x, b = blockIdx.x;
    for (int t = tid; t < HID * (BSTRIDE + 1); t += 512) ((float*)acc)[t] = 0.f;
    for (int t = tid; t < 16 * HID; t += 512) ((float*)pool)[t] = 0.f;
    if (tid < HID) b2s[tid] = b2[tid];
    __syncthreads();

    int e0 = bbase[b], e1 = bbase[b + 1];
    int p = tid & 7, g = tid >> 3;
    for (int t = e0 + g; t < e1; t += 64) {
        int2 pr = binned[t];
        int s = pr.x, dl = pr.y & (BSTRIDE - 1);
        float4 v = Y2[(size_t)s * 8 + p];
        atomicAdd(&acc[4 * p + 0][dl], v.x);
        atomicAdd(&acc[4 * p + 1][dl], v.y);
        atomicAdd(&acc[4 * p + 2][dl], v.z);
        atomicAdd(&acc[4 * p + 3][dl], v.w);
    }
    __syncthreads();

    int i0 = b * BSTRIDE;
    int gFirst = batch[i0];
    if (tid < BSTRIDE) {
        int i = i0 + tid;
        if (i < N_NODES) {
            float di = dinv[i];
            float h[HID];
#pragma unroll
            for (int q = 0; q < 8; ++q) {
                float4 v = Y2[(size_t)i * 8 + q];     // self term
                h[4 * q + 0] = fmaxf(fmaf(di, acc[4 * q + 0][tid] + v.x, b2s[4 * q + 0]), 0.f);
                h[4 * q + 1] = fmaxf(fmaf(di, acc[4 * q + 1][tid] + v.y, b2s[4 * q + 1]), 0.f);
                h[4 * q + 2] = fmaxf(fmaf(di, acc[4 * q + 2][tid] + v.z, b2s[4 * q + 2]), 0.f);
                h[4 * q + 3] = fmaxf(fmaf(di, acc[4 * q + 3][tid] + v.w, b2s[4 * q + 3]), 0.f);
            }
            int gl = batch[i] - gFirst;
            if (gl < 16) {
                for (int st = 0; st < HID; ++st) {     // staggered: no same-addr serialization
                    int c = (tid + st) & 31;
                    atomicAdd(&pool[gl][c], h[c]);
                }
            } else {                                   // paranoia fallback (never expected)
                for (int c = 0; c < HID; ++c)
                    atomicAdd(&pooled[(size_t)batch[i] * HID + c], h[c]);
            }
        }
    }
    __syncthreads();
    int iLast = min(i0 + BSTRIDE - 1, N_NODES - 1);
    int ng = batch[iLast] - gFirst + 1;
    if (ng > 16) ng = 16;
    for (int t = tid; t < ng * HID; t += 512) {
        int gg = t >> 5, c = t & 31;
        float v = pool[gg][c];
        if (v != 0.f) atomicAdd(&pooled[(size_t)(gFirst + gg) * HID + c], v);
    }
}

// head: mean (counts via binary search) -> relu(@Wc1+bc1) -> sigmoid(@Wc2+bc2)
__global__ void k_head(const float* __restrict__ pooled, const int* __restrict__ batch,
                       const float* __restrict__ Wc1, const float* __restrict__ bc1,
                       const float* __restrict__ Wc2, const float* __restrict__ bc2,
                       float* __restrict__ out) {
    int g = blockIdx.x * blockDim.x + threadIdx.x;
    if (g >= N_GRAPHS) return;
    int lo = 0, hi = N_NODES;
    while (lo < hi) { int mid = (lo + hi) >> 1; if (batch[mid] < g) lo = mid + 1; else hi = mid; }
    int start = lo;
    hi = N_NODES;
    while (lo < hi) { int mid = (lo + hi) >> 1; if (batch[mid] < g + 1) lo = mid + 1; else hi = mid; }
    int end = lo;
    float inv = 1.0f / fmaxf((float)(end - start), 1.0f);
    float m[HID];
    for (int j = 0; j < HID; ++j) m[j] = pooled[g * HID + j] * inv;
    float hc[16];
    for (int j = 0; j < 16; ++j) {
        float s = bc1[j];
        for (int k = 0; k < HID; ++k) s = fmaf(m[k], Wc1[k * 16 + j], s);
        hc[j] = fmaxf(s, 0.f);
    }
    float s = bc2[0];
    for (int k = 0; k < 16; ++k) s = fmaf(hc[k], Wc2[k], s);
    out[g] = 1.0f / (1.0f + expf(-s));
}

// ---------------- launch ----------------

extern "C" void kernel_launch(void* const* d_in, const int* in_sizes, int n_in,
                              void* d_out, int out_size, void* d_ws, size_t ws_size,
                              hipStream_t stream) {
    const int*   ids  = (const int*)d_in[0];
    const int*   src  = (const int*)d_in[1];
    const int*   dst  = ((const int*)d_in[1]) + N_EDGES;
    const int*   batch = (const int*)d_in[2];
    const float* emb  = (const float*)d_in[3];
    const float* W1   = (const float*)d_in[4];
    const float* b1   = (const float*)d_in[5];
    const float* W2   = (const float*)d_in[6];
    const float* b2   = (const float*)d_in[7];
    const float* Wc1  = (const float*)d_in[8];
    const float* bc1  = (const float*)d_in[9];
    const float* Wc2  = (const float*)d_in[10];
    const float* bc2  = (const float*)d_in[11];
    float* out = (float*)d_out;

    // workspace layout (16B-aligned head)
    float* Y2    = (float*)d_ws;                        // 3,200,000 f
    int2*  binned = (int2*)(Y2 + (size_t)N_NODES * HID); // 1,000,000 int2
    int*   counts = (int*)(binned + N_EDGES);           // 245*391
    int*   offs   = counts + NBINBLK * NBUCK;           // 245*391
    int*   bbase  = offs + NBINBLK * NBUCK;             // 392
    float* dinv   = (float*)(bbase + NBUCK + 1);        // 100000
    float* table  = dinv + N_NODES;                     // 6400
    float* pooled = table + NUM_TYPES * HID;            // 8192

    hipMemsetAsync(pooled, 0, N_GRAPHS * HID * sizeof(float), stream);

    // bin edges by dst bucket
    k_binA<<<NBINBLK, 256, 0, stream>>>(dst, counts);
    k_binScan<<<1, 512, 0, stream>>>(counts, offs, bbase);
    k_binB<<<NBINBLK, 256, 0, stream>>>(src, dst, offs, binned);
    k_deg<<<NBUCK, 256, 0, stream>>>(binned, bbase, dinv);

    // layer-1 table (emb @ W1)
    k_table<<<(NUM_TYPES * HID + 255) / 256, 256, 0, stream>>>(emb, W1, table);

    // fused layers
    k_gather1<<<NBUCK, 512, 0, stream>>>(binned, bbase, ids, dinv, table, W2, b1,
                                         (float4*)Y2);
    k_gather2<<<NBUCK, 512, 0, stream>>>(binned, bbase, (const float4*)Y2, dinv, b2,
                                         batch, pooled);
    // head
    k_head<<<1, N_GRAPHS, 0, stream>>>(pooled, batch, Wc1, bc1, Wc2, bc2, out);
}

// Round 6
// 148.885 us; speedup vs baseline: 3.8326x; 3.8326x over previous
//
#include <hip/hip_runtime.h>
#include <math.h>

#define N_NODES   100000
#define N_EDGES   1000000
#define N_GRAPHS  256
#define NUM_TYPES 200
#define EMB       64
#define HID       32

#define BSHIFT    8
#define BSTRIDE   256                                   // nodes per bucket
#define NBUCK     ((N_NODES + BSTRIDE - 1) / BSTRIDE)   // 391
#define EPB       4096                                  // edges per bin block
#define NBINBLK   ((N_EDGES + EPB - 1) / EPB)           // 245
#define MAXBE     4096                                  // max edges per bucket (mean 2560, +30 sigma)

// ---------------- binning -> per-node CSR ----------------

// per-block bucket histogram -> counts[k*NBUCK + b]
__global__ __launch_bounds__(256) void k_binA(const int* __restrict__ dst,
                                              int* __restrict__ counts) {
    __shared__ int cnt[NBUCK];
    int tid = threadIdx.x, k = blockIdx.x;
    for (int b = tid; b < NBUCK; b += 256) cnt[b] = 0;
    __syncthreads();
    int base = k * EPB;
    int n = min(EPB, N_EDGES - base);
    for (int t = tid; t < n; t += 256) atomicAdd(&cnt[dst[base + t] >> BSHIFT], 1);
    __syncthreads();
    for (int b = tid; b < NBUCK; b += 256) counts[k * NBUCK + b] = cnt[b];
}

// one block: absolute offsets offs[k*NBUCK+b] and bucket bases bbase[0..NBUCK]
__global__ __launch_bounds__(512) void k_binScan(const int* __restrict__ counts,
                                                 int* __restrict__ offs,
                                                 int* __restrict__ bbase) {
    __shared__ int sA[512], sB[512];
    int tid = threadIdx.x;
    int total = 0;
    if (tid < NBUCK)
        for (int k = 0; k < NBINBLK; ++k) total += counts[k * NBUCK + tid];
    sA[tid] = (tid < NBUCK) ? total : 0;
    __syncthreads();
    int* in = sA; int* out = sB;
    for (int off = 1; off < 512; off <<= 1) {
        out[tid] = in[tid] + (tid >= off ? in[tid - off] : 0);
        __syncthreads();
        int* tmp = in; in = out; out = tmp;
    }
    int excl = in[tid] - ((tid < NBUCK) ? total : 0);
    if (tid < NBUCK) {
        bbase[tid] = excl;
        int run = excl;
        for (int k = 0; k < NBINBLK; ++k) {
            offs[k * NBUCK + tid] = run;
            run += counts[k * NBUCK + tid];
        }
    }
    if (tid == 0) bbase[NBUCK] = N_EDGES;
}

// LDS counting-sort by bucket within each block; coalesced write of (src,dst)
// pairs into bucket-grouped global order.
__global__ __launch_bounds__(256) void k_binB(const int* __restrict__ src,
                                              const int* __restrict__ dst,
                                              const int* __restrict__ offs,
                                              int2* __restrict__ binned) {
    __shared__ int srcl[EPB];
    __shared__ int dstl[EPB];
    __shared__ unsigned short rank16[EPB];
    __shared__ unsigned short perm[EPB];
    __shared__ int cnt[NBUCK];
    __shared__ int loc[NBUCK];
    __shared__ int offsL[NBUCK];
    __shared__ int sA[512], sB[512];
    int tid = threadIdx.x, k = blockIdx.x;
    int base = k * EPB;
    int n = min(EPB, N_EDGES - base);
    for (int b = tid; b < NBUCK; b += 256) { cnt[b] = 0; offsL[b] = offs[k * NBUCK + b]; }
    __syncthreads();
    for (int t = tid; t < n; t += 256) {
        int s = src[base + t], d = dst[base + t];
        srcl[t] = s; dstl[t] = d;
        rank16[t] = (unsigned short)atomicAdd(&cnt[d >> BSHIFT], 1);
    }
    __syncthreads();
    for (int t = tid; t < 512; t += 256) sA[t] = (t < NBUCK) ? cnt[t] : 0;
    __syncthreads();
    int* in = sA; int* out = sB;
    for (int off = 1; off < 512; off <<= 1) {
        for (int t = tid; t < 512; t += 256)
            out[t] = in[t] + (t >= off ? in[t - off] : 0);
        __syncthreads();
        int* tmp = in; in = out; out = tmp;
    }
    for (int b = tid; b < NBUCK; b += 256) loc[b] = in[b] - cnt[b];
    __syncthreads();
    for (int t = tid; t < n; t += 256) {
        int b = dstl[t] >> BSHIFT;
        perm[loc[b] + rank16[t]] = (unsigned short)t;
    }
    __syncthreads();
    for (int t = tid; t < n; t += 256) {
        int e = perm[t];
        int d = dstl[e], b = d >> BSHIFT;
        int gpos = offsL[b] + (t - loc[b]);
        binned[gpos] = make_int2(srcl[e], d);
    }
}

// one block per bucket: LDS counting-sort by node -> coalesced ssrc writes,
// plus row_ptr / deg / dinv.
__global__ __launch_bounds__(256) void k_csr(const int2* __restrict__ binned,
                                             const int* __restrict__ bbase,
                                             int* __restrict__ ssrc,
                                             int* __restrict__ row_ptr,
                                             int* __restrict__ deg_g,
                                             float* __restrict__ dinv) {
    __shared__ int srcl[MAXBE];
    __shared__ unsigned char dl[MAXBE];
    __shared__ unsigned short rank16[MAXBE];
    __shared__ unsigned short perm[MAXBE];
    __shared__ int degL[BSTRIDE];
    __shared__ int loc[BSTRIDE];
    __shared__ int sA[BSTRIDE], sB[BSTRIDE];
    int tid = threadIdx.x, b = blockIdx.x;
    int e0 = bbase[b], e1 = bbase[b + 1];
    int n = e1 - e0;
    degL[tid] = 0;
    __syncthreads();
    for (int t = tid; t < n; t += 256) {
        int2 pr = binned[e0 + t];
        srcl[t] = pr.x;
        int d = pr.y & (BSTRIDE - 1);
        dl[t] = (unsigned char)d;
        rank16[t] = (unsigned short)atomicAdd(&degL[d], 1);
    }
    __syncthreads();
    // exclusive scan of degL (Hillis-Steele, 256)
    sA[tid] = degL[tid];
    __syncthreads();
    int* in = sA; int* out = sB;
    for (int off = 1; off < 256; off <<= 1) {
        out[tid] = in[tid] + (tid >= off ? in[tid - off] : 0);
        __syncthreads();
        int* tmp = in; in = out; out = tmp;
    }
    loc[tid] = in[tid] - degL[tid];
    __syncthreads();
    for (int t = tid; t < n; t += 256)
        perm[loc[dl[t]] + rank16[t]] = (unsigned short)t;
    __syncthreads();
    for (int t = tid; t < n; t += 256)
        ssrc[e0 + t] = srcl[perm[t]];
    int i = b * BSTRIDE + tid;
    if (i < N_NODES) {
        row_ptr[i] = e0 + loc[tid];
        deg_g[i] = degL[tid];
        dinv[i] = rsqrtf((float)degL[tid] + 1.0f);
    }
}

// ---------------- feature pipeline ----------------

// table[t][j] = sum_k emb[t][k] * W1[k][j]   (200 x 32)
__global__ void k_table(const float* __restrict__ emb, const float* __restrict__ W1,
                        float* __restrict__ table) {
    int i = blockIdx.x * blockDim.x + threadIdx.x;
    if (i >= NUM_TYPES * HID) return;
    int t = i / HID, j = i % HID;
    float s = 0.f;
    for (int k = 0; k < EMB; ++k) s = fmaf(emb[t * EMB + k], W1[k * HID + j], s);
    table[i] = s;
}

// Layer 1 + layer-2 producer, fused; 8 lanes/node, 4-way pipelined edge loop.
__global__ __launch_bounds__(256) void k_gather1(
        const int* __restrict__ ids, const float* __restrict__ table,
        const int* __restrict__ row_ptr, const int* __restrict__ deg,
        const int* __restrict__ ssrc, const float* __restrict__ dinv,
        const float* __restrict__ b1, const float* __restrict__ W2,
        float4* __restrict__ Y2) {
    __shared__ float w[HID * HID];
    for (int k = threadIdx.x; k < HID * HID; k += blockDim.x) w[k] = W2[k];
    __syncthreads();

    int t = blockIdx.x * blockDim.x + threadIdx.x;   // exact grid: 800000
    int i = t >> 3, p = t & 7;
    const float4* tab4 = (const float4*)table;

    float di = dinv[i];
    float4 acc = tab4[ids[i] * 8 + p];               // self term
    acc.x *= di; acc.y *= di; acc.z *= di; acc.w *= di;

    int s0 = row_ptr[i], n = deg[i];
    int e = 0;
    for (; e + 4 <= n; e += 4) {
        int sa = ssrc[s0 + e + 0], sb = ssrc[s0 + e + 1];
        int sc = ssrc[s0 + e + 2], sd = ssrc[s0 + e + 3];
        float da = dinv[sa], db = dinv[sb], dc = dinv[sc], dd = dinv[sd];
        int ia = ids[sa], ib = ids[sb], ic = ids[sc], id_ = ids[sd];
        float4 va = tab4[ia * 8 + p], vb = tab4[ib * 8 + p];
        float4 vc = tab4[ic * 8 + p], vd = tab4[id_ * 8 + p];
        acc.x = fmaf(va.x, da, acc.x); acc.y = fmaf(va.y, da, acc.y);
        acc.z = fmaf(va.z, da, acc.z); acc.w = fmaf(va.w, da, acc.w);
        acc.x = fmaf(vb.x, db, acc.x); acc.y = fmaf(vb.y, db, acc.y);
        acc.z = fmaf(vb.z, db, acc.z); acc.w = fmaf(vb.w, db, acc.w);
        acc.x = fmaf(vc.x, dc, acc.x); acc.y = fmaf(vc.y, dc, acc.y);
        acc.z = fmaf(vc.z, dc, acc.z); acc.w = fmaf(vc.w, dc, acc.w);
        acc.x = fmaf(vd.x, dd, acc.x); acc.y = fmaf(vd.y, dd, acc.y);
        acc.z = fmaf(vd.z, dd, acc.z); acc.w = fmaf(vd.w, dd, acc.w);
    }
    for (; e < n; ++e) {
        int s = ssrc[s0 + e];
        float ds = dinv[s];
        float4 v = tab4[ids[s] * 8 + p];
        acc.x = fmaf(v.x, ds, acc.x); acc.y = fmaf(v.y, ds, acc.y);
        acc.z = fmaf(v.z, ds, acc.z); acc.w = fmaf(v.w, ds, acc.w);
    }
    float4 bb = ((const float4*)b1)[p];
    float4 h;
    h.x = fmaxf(fmaf(di, acc.x, bb.x), 0.f);
    h.y = fmaxf(fmaf(di, acc.y, bb.y), 0.f);
    h.z = fmaxf(fmaf(di, acc.z, bb.z), 0.f);
    h.w = fmaxf(fmaf(di, acc.w, bb.w), 0.f);

    // out[4p+c] = sum_k h[k] * W2[k][4p+c] via intra-8-lane shuffles
    float o0 = 0.f, o1 = 0.f, o2 = 0.f, o3 = 0.f;
    const float4* w4 = (const float4*)w;
#pragma unroll
    for (int q = 0; q < 8; ++q) {
        float4 hq;
        hq.x = __shfl(h.x, q, 8);
        hq.y = __shfl(h.y, q, 8);
        hq.z = __shfl(h.z, q, 8);
        hq.w = __shfl(h.w, q, 8);
        float4 w0 = w4[(4 * q + 0) * 8 + p];
        float4 w1 = w4[(4 * q + 1) * 8 + p];
        float4 w2 = w4[(4 * q + 2) * 8 + p];
        float4 w3 = w4[(4 * q + 3) * 8 + p];
        o0 = fmaf(hq.x, w0.x, o0); o1 = fmaf(hq.x, w0.y, o1); o2 = fmaf(hq.x, w0.z, o2); o3 = fmaf(hq.x, w0.w, o3);
        o0 = fmaf(hq.y, w1.x, o0); o1 = fmaf(hq.y, w1.y, o1); o2 = fmaf(hq.y, w1.z, o2); o3 = fmaf(hq.y, w1.w, o3);
        o0 = fmaf(hq.z, w2.x, o0); o1 = fmaf(hq.z, w2.y, o1); o2 = fmaf(hq.z, w2.z, o2); o3 = fmaf(hq.z, w2.w, o3);
        o0 = fmaf(hq.w, w3.x, o0); o1 = fmaf(hq.w, w3.y, o1); o2 = fmaf(hq.w, w3.z, o2); o3 = fmaf(hq.w, w3.w, o3);
    }
    float4 yv;
    yv.x = o0 * di; yv.y = o1 * di; yv.z = o2 * di; yv.w = o3 * di;
    Y2[i * 8 + p] = yv;
}

// Layer 2 + fused mean-pool partial sums (batch is sorted); 4-way pipelined.
__global__ __launch_bounds__(256) void k_gather2(
        const float4* __restrict__ Y2, const int* __restrict__ row_ptr,
        const int* __restrict__ deg, const int* __restrict__ ssrc,
        const float* __restrict__ dinv, const float* __restrict__ b2,
        const int* __restrict__ batch, float* __restrict__ pooled) {
    __shared__ float lp[32][HID];                    // per-block per-graph partials
    for (int k = threadIdx.x; k < 32 * HID; k += blockDim.x) ((float*)lp)[k] = 0.f;
    __syncthreads();

    int t = blockIdx.x * blockDim.x + threadIdx.x;
    int i = t >> 3, p = t & 7;
    int i0 = (blockIdx.x * blockDim.x) >> 3;         // first node of block
    int gFirst = batch[i0];

    float4 acc = Y2[i * 8 + p];                      // self term
    int s0 = row_ptr[i], n = deg[i];
    int e = 0;
    for (; e + 4 <= n; e += 4) {
        int sa = ssrc[s0 + e + 0], sb = ssrc[s0 + e + 1];
        int sc = ssrc[s0 + e + 2], sd = ssrc[s0 + e + 3];
        float4 va = Y2[sa * 8 + p], vb = Y2[sb * 8 + p];
        float4 vc = Y2[sc * 8 + p], vd = Y2[sd * 8 + p];
        acc.x += va.x + vb.x + vc.x + vd.x;
        acc.y += va.y + vb.y + vc.y + vd.y;
        acc.z += va.z + vb.z + vc.z + vd.z;
        acc.w += va.w + vb.w + vc.w + vd.w;
    }
    for (; e < n; ++e) {
        int s = ssrc[s0 + e];
        float4 v = Y2[s * 8 + p];
        acc.x += v.x; acc.y += v.y; acc.z += v.z; acc.w += v.w;
    }
    float di = dinv[i];
    float4 bb = ((const float4*)b2)[p];
    float4 h;
    h.x = fmaxf(fmaf(di, acc.x, bb.x), 0.f);
    h.y = fmaxf(fmaf(di, acc.y, bb.y), 0.f);
    h.z = fmaxf(fmaf(di, acc.z, bb.z), 0.f);
    h.w = fmaxf(fmaf(di, acc.w, bb.w), 0.f);

    int gl = batch[i] - gFirst;                      // 0..31 within block
    atomicAdd(&lp[gl][p * 4 + 0], h.x);
    atomicAdd(&lp[gl][p * 4 + 1], h.y);
    atomicAdd(&lp[gl][p * 4 + 2], h.z);
    atomicAdd(&lp[gl][p * 4 + 3], h.w);
    __syncthreads();

    int gLast = batch[i0 + 31];
    int ng = gLast - gFirst + 1;
    for (int k = threadIdx.x; k < ng * HID; k += blockDim.x) {
        float v = lp[k / HID][k % HID];
        if (v != 0.f) atomicAdd(&pooled[(gFirst + k / HID) * HID + (k % HID)], v);
    }
}

// head: mean (counts via binary search) -> relu(@Wc1+bc1) -> sigmoid(@Wc2+bc2)
__global__ void k_head(const float* __restrict__ pooled, const int* __restrict__ batch,
                       const float* __restrict__ Wc1, const float* __restrict__ bc1,
                       const float* __restrict__ Wc2, const float* __restrict__ bc2,
                       float* __restrict__ out) {
    int g = blockIdx.x * blockDim.x + threadIdx.x;
    if (g >= N_GRAPHS) return;
    int lo = 0, hi = N_NODES;
    while (lo < hi) { int mid = (lo + hi) >> 1; if (batch[mid] < g) lo = mid + 1; else hi = mid; }
    int start = lo;
    hi = N_NODES;
    while (lo < hi) { int mid = (lo + hi) >> 1; if (batch[mid] < g + 1) lo = mid + 1; else hi = mid; }
    int end = lo;
    float inv = 1.0f / fmaxf((float)(end - start), 1.0f);
    float m[HID];
    for (int j = 0; j < HID; ++j) m[j] = pooled[g * HID + j] * inv;
    float hc[16];
    for (int j = 0; j < 16; ++j) {
        float s = bc1[j];
        for (int k = 0; k < HID; ++k) s = fmaf(m[k], Wc1[k * 16 + j], s);
        hc[j] = fmaxf(s, 0.f);
    }
    float s = bc2[0];
    for (int k = 0; k < 16; ++k) s = fmaf(hc[k], Wc2[k], s);
    out[g] = 1.0f / (1.0f + expf(-s));
}

// ---------------- launch ----------------

extern "C" void kernel_launch(void* const* d_in, const int* in_sizes, int n_in,
                              void* d_out, int out_size, void* d_ws, size_t ws_size,
                              hipStream_t stream) {
    const int*   ids  = (const int*)d_in[0];
    const int*   src  = (const int*)d_in[1];
    const int*   dst  = ((const int*)d_in[1]) + N_EDGES;
    const int*   batch = (const int*)d_in[2];
    const float* emb  = (const float*)d_in[3];
    const float* W1   = (const float*)d_in[4];
    const float* b1   = (const float*)d_in[5];
    const float* W2   = (const float*)d_in[6];
    const float* b2   = (const float*)d_in[7];
    const float* Wc1  = (const float*)d_in[8];
    const float* bc1  = (const float*)d_in[9];
    const float* Wc2  = (const float*)d_in[10];
    const float* bc2  = (const float*)d_in[11];
    float* out = (float*)d_out;

    // workspace layout (16B-aligned head)
    float* Y2     = (float*)d_ws;                         // 3,200,000 f
    int2*  binned = (int2*)(Y2 + (size_t)N_NODES * HID);  // 1,000,000 int2
    int*   ssrc   = (int*)(binned + N_EDGES);             // 1,000,000
    int*   counts = ssrc + N_EDGES;                       // 245*391
    int*   offs   = counts + NBINBLK * NBUCK;             // 245*391
    int*   bbase  = offs + NBINBLK * NBUCK;               // 392
    int*   row_ptr = bbase + NBUCK + 1;                   // 100000
    int*   deg    = row_ptr + N_NODES;                    // 100000
    float* dinv   = (float*)(deg + N_NODES);              // 100000
    float* table  = dinv + N_NODES;                       // 6400
    float* pooled = table + NUM_TYPES * HID;              // 8192

    const int B = 256;
    const int gNode8 = (N_NODES * 8) / B;       // exact: 3125

    hipMemsetAsync(pooled, 0, N_GRAPHS * HID * sizeof(float), stream);

    // CSR build via bucket binning (coalesced writes)
    k_binA<<<NBINBLK, B, 0, stream>>>(dst, counts);
    k_binScan<<<1, 512, 0, stream>>>(counts, offs, bbase);
    k_binB<<<NBINBLK, B, 0, stream>>>(src, dst, offs, binned);
    k_csr<<<NBUCK, B, 0, stream>>>(binned, bbase, ssrc, row_ptr, deg, dinv);

    // layer-1 table (emb @ W1)
    k_table<<<(NUM_TYPES * HID + B - 1) / B, B, 0, stream>>>(emb, W1, table);

    // fused layer1 + W2 producer
    k_gather1<<<gNode8, B, 0, stream>>>(ids, table, row_ptr, deg, ssrc, dinv, b1, W2,
                                        (float4*)Y2);
    // fused layer2 + pooling
    k_gather2<<<gNode8, B, 0, stream>>>((const float4*)Y2, row_ptr, deg, ssrc, dinv, b2,
                                        batch, pooled);
    // head
    k_head<<<1, N_GRAPHS, 0, stream>>>(pooled, batch, Wc1, bc1, Wc2, bc2, out);
}

// Round 7
// 127.288 us; speedup vs baseline: 4.4829x; 1.1697x over previous
//
#include <hip/hip_runtime.h>
#include <math.h>

#define N_NODES   100000
#define N_EDGES   1000000
#define N_GRAPHS  256
#define NUM_TYPES 200
#define EMB       64
#define HID       32

#define BSHIFT    8
#define BSTRIDE   256                                   // nodes per bucket
#define NBUCK     ((N_NODES + BSTRIDE - 1) / BSTRIDE)   // 391
#define EPB       4096                                  // edges per bin block
#define NBINBLK   ((N_EDGES + EPB - 1) / EPB)           // 245
#define MAXBE     4096                                  // max edges per bucket (mean 2560)
#define SRCBITS   17                                    // 100000 < 2^17
#define SRCMASK   0x1FFFF

// ---------------- binning -> per-node CSR ----------------

// per-block bucket histogram -> counts[k*NBUCK + b]
__global__ __launch_bounds__(256) void k_binA(const int* __restrict__ dst,
                                              int* __restrict__ counts) {
    __shared__ int cnt[NBUCK];
    int tid = threadIdx.x, k = blockIdx.x;
    for (int b = tid; b < NBUCK; b += 256) cnt[b] = 0;
    __syncthreads();
    int base = k * EPB;
    int n = min(EPB, N_EDGES - base);
    for (int t = tid; t < n; t += 256) atomicAdd(&cnt[dst[base + t] >> BSHIFT], 1);
    __syncthreads();
    for (int b = tid; b < NBUCK; b += 256) counts[k * NBUCK + b] = cnt[b];
}

// block 0: scan -> offs/bbase; block 1: table = emb@W1; block 2: zero pooled
__global__ __launch_bounds__(512) void k_misc(const int* __restrict__ counts,
                                              int* __restrict__ offs,
                                              int* __restrict__ bbase,
                                              const float* __restrict__ emb,
                                              const float* __restrict__ W1,
                                              float* __restrict__ table,
                                              float* __restrict__ pooled) {
    int tid = threadIdx.x;
    if (blockIdx.x == 0) {
        __shared__ int sA[512], sB[512];
        int total = 0;
        if (tid < NBUCK)
            for (int k = 0; k < NBINBLK; ++k) total += counts[k * NBUCK + tid];
        sA[tid] = (tid < NBUCK) ? total : 0;
        __syncthreads();
        int* in = sA; int* out = sB;
        for (int off = 1; off < 512; off <<= 1) {
            out[tid] = in[tid] + (tid >= off ? in[tid - off] : 0);
            __syncthreads();
            int* tmp = in; in = out; out = tmp;
        }
        int excl = in[tid] - ((tid < NBUCK) ? total : 0);
        if (tid < NBUCK) {
            bbase[tid] = excl;
            int run = excl;
            for (int k = 0; k < NBINBLK; ++k) {
                offs[k * NBUCK + tid] = run;
                run += counts[k * NBUCK + tid];
            }
        }
        if (tid == 0) bbase[NBUCK] = N_EDGES;
    } else if (blockIdx.x == 1) {
        for (int t = tid; t < NUM_TYPES * HID; t += 512) {
            int ty = t / HID, j = t % HID;
            float s = 0.f;
            for (int k = 0; k < EMB; ++k) s = fmaf(emb[ty * EMB + k], W1[k * HID + j], s);
            table[t] = s;
        }
    } else {
        for (int t = tid; t < N_GRAPHS * HID; t += 512) pooled[t] = 0.f;
    }
}

// LDS counting-sort by bucket within each block; packed (dlow<<17)|src output
__global__ __launch_bounds__(256) void k_binB(const int* __restrict__ src,
                                              const int* __restrict__ dst,
                                              const int* __restrict__ offs,
                                              int* __restrict__ binned) {
    __shared__ int srcl[EPB];
    __shared__ int dstl[EPB];
    __shared__ unsigned short rank16[EPB];
    __shared__ unsigned short perm[EPB];
    __shared__ int cnt[NBUCK];
    __shared__ int loc[NBUCK];
    __shared__ int offsL[NBUCK];
    __shared__ int sA[512], sB[512];
    int tid = threadIdx.x, k = blockIdx.x;
    int base = k * EPB;
    int n = min(EPB, N_EDGES - base);
    for (int b = tid; b < NBUCK; b += 256) { cnt[b] = 0; offsL[b] = offs[k * NBUCK + b]; }
    __syncthreads();
    for (int t = tid; t < n; t += 256) {
        int s = src[base + t], d = dst[base + t];
        srcl[t] = s; dstl[t] = d;
        rank16[t] = (unsigned short)atomicAdd(&cnt[d >> BSHIFT], 1);
    }
    __syncthreads();
    for (int t = tid; t < 512; t += 256) sA[t] = (t < NBUCK) ? cnt[t] : 0;
    __syncthreads();
    int* in = sA; int* out = sB;
    for (int off = 1; off < 512; off <<= 1) {
        for (int t = tid; t < 512; t += 256)
            out[t] = in[t] + (t >= off ? in[t - off] : 0);
        __syncthreads();
        int* tmp = in; in = out; out = tmp;
    }
    for (int b = tid; b < NBUCK; b += 256) loc[b] = in[b] - cnt[b];
    __syncthreads();
    for (int t = tid; t < n; t += 256) {
        int b = dstl[t] >> BSHIFT;
        perm[loc[b] + rank16[t]] = (unsigned short)t;
    }
    __syncthreads();
    for (int t = tid; t < n; t += 256) {
        int e = perm[t];
        int d = dstl[e], b = d >> BSHIFT;
        int gpos = offsL[b] + (t - loc[b]);
        binned[gpos] = ((d & (BSTRIDE - 1)) << SRCBITS) | srcl[e];
    }
}

// one block per bucket: sort by node -> ssrc (coalesced), row_ptr, dinv, nodeinfo
__global__ __launch_bounds__(256) void k_csr(const int* __restrict__ binned,
                                             const int* __restrict__ bbase,
                                             const int* __restrict__ ids,
                                             int* __restrict__ ssrc,
                                             int* __restrict__ row_ptr,
                                             float* __restrict__ dinv,
                                             int2* __restrict__ nodeinfo) {
    __shared__ int pk[MAXBE];
    __shared__ unsigned char dl[MAXBE];
    __shared__ unsigned short rank16[MAXBE];
    __shared__ unsigned short perm[MAXBE];
    __shared__ int degL[BSTRIDE];
    __shared__ int loc[BSTRIDE];
    __shared__ int sA[BSTRIDE], sB[BSTRIDE];
    int tid = threadIdx.x, b = blockIdx.x;
    int e0 = bbase[b], e1 = bbase[b + 1];
    int n = min(e1 - e0, MAXBE);
    degL[tid] = 0;
    __syncthreads();
    for (int t = tid; t < n; t += 256) {
        int v = binned[e0 + t];
        pk[t] = v;
        int d = v >> SRCBITS;
        dl[t] = (unsigned char)d;
        rank16[t] = (unsigned short)atomicAdd(&degL[d], 1);
    }
    __syncthreads();
    sA[tid] = degL[tid];
    __syncthreads();
    int* in = sA; int* out = sB;
    for (int off = 1; off < 256; off <<= 1) {
        out[tid] = in[tid] + (tid >= off ? in[tid - off] : 0);
        __syncthreads();
        int* tmp = in; in = out; out = tmp;
    }
    loc[tid] = in[tid] - degL[tid];
    __syncthreads();
    for (int t = tid; t < n; t += 256)
        perm[loc[dl[t]] + rank16[t]] = (unsigned short)t;
    __syncthreads();
    for (int t = tid; t < n; t += 256)
        ssrc[e0 + t] = pk[perm[t]] & SRCMASK;
    int i = b * BSTRIDE + tid;
    if (i < N_NODES) {
        row_ptr[i] = e0 + loc[tid];
        float dv = rsqrtf((float)degL[tid] + 1.0f);
        dinv[i] = dv;
        nodeinfo[i] = make_int2(ids[i], __float_as_int(dv));
    }
    if (b == NBUCK - 1 && tid == 0) row_ptr[N_NODES] = N_EDGES;
}

// ---------------- feature pipeline ----------------

// Layer 1 + layer-2 producer, fused; 8 lanes/node, 8-deep pipelined edge loop.
__global__ __launch_bounds__(256) void k_gather1(
        const int2* __restrict__ nodeinfo, const float* __restrict__ table,
        const int* __restrict__ row_ptr, const int* __restrict__ ssrc,
        const float* __restrict__ b1, const float* __restrict__ W2,
        float4* __restrict__ Y2) {
    __shared__ float w[HID * HID];
    for (int k = threadIdx.x; k < HID * HID; k += 256) w[k] = W2[k];
    __syncthreads();

    int t = blockIdx.x * 256 + threadIdx.x;          // exact grid: 800000
    int i = t >> 3, p = t & 7;
    const float4* tab4 = (const float4*)table;

    int s0 = row_ptr[i], n = row_ptr[i + 1] - s0;
    int2 self = nodeinfo[i];
    float di = __int_as_float(self.y);
    float4 acc = tab4[self.x * 8 + p];               // self term
    acc.x *= di; acc.y *= di; acc.z *= di; acc.w *= di;

    for (int e = 0; e < n; e += 8) {
        int ss[8];
        int2 ni[8];
#pragma unroll
        for (int u = 0; u < 8; ++u) {
            int idx = e + u; idx = (idx > n - 1) ? n - 1 : idx;
            ss[u] = ssrc[s0 + idx];
        }
#pragma unroll
        for (int u = 0; u < 8; ++u) ni[u] = nodeinfo[ss[u]];
#pragma unroll
        for (int u = 0; u < 8; ++u) {
            float ds = (e + u < n) ? __int_as_float(ni[u].y) : 0.f;
            float4 v = tab4[ni[u].x * 8 + p];
            acc.x = fmaf(v.x, ds, acc.x);
            acc.y = fmaf(v.y, ds, acc.y);
            acc.z = fmaf(v.z, ds, acc.z);
            acc.w = fmaf(v.w, ds, acc.w);
        }
    }
    float4 bb = ((const float4*)b1)[p];
    float4 h;
    h.x = fmaxf(fmaf(di, acc.x, bb.x), 0.f);
    h.y = fmaxf(fmaf(di, acc.y, bb.y), 0.f);
    h.z = fmaxf(fmaf(di, acc.z, bb.z), 0.f);
    h.w = fmaxf(fmaf(di, acc.w, bb.w), 0.f);

    // out[4p+c] = sum_k h[k] * W2[k][4p+c] via intra-8-lane shuffles
    float o0 = 0.f, o1 = 0.f, o2 = 0.f, o3 = 0.f;
    const float4* w4 = (const float4*)w;
#pragma unroll
    for (int q = 0; q < 8; ++q) {
        float4 hq;
        hq.x = __shfl(h.x, q, 8);
        hq.y = __shfl(h.y, q, 8);
        hq.z = __shfl(h.z, q, 8);
        hq.w = __shfl(h.w, q, 8);
        float4 w0 = w4[(4 * q + 0) * 8 + p];
        float4 w1 = w4[(4 * q + 1) * 8 + p];
        float4 w2 = w4[(4 * q + 2) * 8 + p];
        float4 w3 = w4[(4 * q + 3) * 8 + p];
        o0 = fmaf(hq.x, w0.x, o0); o1 = fmaf(hq.x, w0.y, o1); o2 = fmaf(hq.x, w0.z, o2); o3 = fmaf(hq.x, w0.w, o3);
        o0 = fmaf(hq.y, w1.x, o0); o1 = fmaf(hq.y, w1.y, o1); o2 = fmaf(hq.y, w1.z, o2); o3 = fmaf(hq.y, w1.w, o3);
        o0 = fmaf(hq.z, w2.x, o0); o1 = fmaf(hq.z, w2.y, o1); o2 = fmaf(hq.z, w2.z, o2); o3 = fmaf(hq.z, w2.w, o3);
        o0 = fmaf(hq.w, w3.x, o0); o1 = fmaf(hq.w, w3.y, o1); o2 = fmaf(hq.w, w3.z, o2); o3 = fmaf(hq.w, w3.w, o3);
    }
    float4 yv;
    yv.x = o0 * di; yv.y = o1 * di; yv.z = o2 * di; yv.w = o3 * di;
    Y2[i * 8 + p] = yv;
}

// Layer 2 + fused mean-pool partial sums (batch sorted); 8-deep pipelined.
__global__ __launch_bounds__(256) void k_gather2(
        const float4* __restrict__ Y2, const int* __restrict__ row_ptr,
        const int* __restrict__ ssrc, const float* __restrict__ dinv,
        const float* __restrict__ b2, const int* __restrict__ batch,
        float* __restrict__ pooled) {
    __shared__ float lp[32][HID];                    // per-block per-graph partials
    for (int k = threadIdx.x; k < 32 * HID; k += 256) ((float*)lp)[k] = 0.f;
    __syncthreads();

    int t = blockIdx.x * 256 + threadIdx.x;
    int i = t >> 3, p = t & 7;
    int i0 = (blockIdx.x * 256) >> 3;                // first node of block
    int gFirst = batch[i0];

    float4 acc = Y2[i * 8 + p];                      // self term
    int s0 = row_ptr[i], n = row_ptr[i + 1] - s0;
    for (int e = 0; e < n; e += 8) {
        int ss[8];
#pragma unroll
        for (int u = 0; u < 8; ++u) {
            int idx = e + u; idx = (idx > n - 1) ? n - 1 : idx;
            ss[u] = ssrc[s0 + idx];
        }
        float4 v[8];
#pragma unroll
        for (int u = 0; u < 8; ++u) v[u] = Y2[ss[u] * 8 + p];
#pragma unroll
        for (int u = 0; u < 8; ++u) {
            float wg = (e + u < n) ? 1.f : 0.f;
            acc.x = fmaf(v[u].x, wg, acc.x);
            acc.y = fmaf(v[u].y, wg, acc.y);
            acc.z = fmaf(v[u].z, wg, acc.z);
            acc.w = fmaf(v[u].w, wg, acc.w);
        }
    }
    float di = dinv[i];
    float4 bb = ((const float4*)b2)[p];
    float4 h;
    h.x = fmaxf(fmaf(di, acc.x, bb.x), 0.f);
    h.y = fmaxf(fmaf(di, acc.y, bb.y), 0.f);
    h.z = fmaxf(fmaf(di, acc.z, bb.z), 0.f);
    h.w = fmaxf(fmaf(di, acc.w, bb.w), 0.f);

    int gl = batch[i] - gFirst;                      // 0..31 within block
    atomicAdd(&lp[gl][p * 4 + 0], h.x);
    atomicAdd(&lp[gl][p * 4 + 1], h.y);
    atomicAdd(&lp[gl][p * 4 + 2], h.z);
    atomicAdd(&lp[gl][p * 4 + 3], h.w);
    __syncthreads();

    int gLast = batch[i0 + 31];
    int ng = gLast - gFirst + 1;
    for (int k = threadIdx.x; k < ng * HID; k += 256) {
        float v = lp[k / HID][k % HID];
        if (v != 0.f) atomicAdd(&pooled[(gFirst + k / HID) * HID + (k % HID)], v);
    }
}

// head: mean (counts via binary search) -> relu(@Wc1+bc1) -> sigmoid(@Wc2+bc2)
__global__ void k_head(const float* __restrict__ pooled, const int* __restrict__ batch,
                       const float* __restrict__ Wc1, const float* __restrict__ bc1,
                       const float* __restrict__ Wc2, const float* __restrict__ bc2,
                       float* __restrict__ out) {
    int g = blockIdx.x * blockDim.x + threadIdx.x;
    if (g >= N_GRAPHS) return;
    int lo = 0, hi = N_NODES;
    while (lo < hi) { int mid = (lo + hi) >> 1; if (batch[mid] < g) lo = mid + 1; else hi = mid; }
    int start = lo;
    hi = N_NODES;
    while (lo < hi) { int mid = (lo + hi) >> 1; if (batch[mid] < g + 1) lo = mid + 1; else hi = mid; }
    int end = lo;
    float inv = 1.0f / fmaxf((float)(end - start), 1.0f);
    float m[HID];
    for (int j = 0; j < HID; ++j) m[j] = pooled[g * HID + j] * inv;
    float hc[16];
    for (int j = 0; j < 16; ++j) {
        float s = bc1[j];
        for (int k = 0; k < HID; ++k) s = fmaf(m[k], Wc1[k * 16 + j], s);
        hc[j] = fmaxf(s, 0.f);
    }
    float s = bc2[0];
    for (int k = 0; k < 16; ++k) s = fmaf(hc[k], Wc2[k], s);
    out[g] = 1.0f / (1.0f + expf(-s));
}

// ---------------- launch ----------------

extern "C" void kernel_launch(void* const* d_in, const int* in_sizes, int n_in,
                              void* d_out, int out_size, void* d_ws, size_t ws_size,
                              hipStream_t stream) {
    const int*   ids  = (const int*)d_in[0];
    const int*   src  = (const int*)d_in[1];
    const int*   dst  = ((const int*)d_in[1]) + N_EDGES;
    const int*   batch = (const int*)d_in[2];
    const float* emb  = (const float*)d_in[3];
    const float* W1   = (const float*)d_in[4];
    const float* b1   = (const float*)d_in[5];
    const float* W2   = (const float*)d_in[6];
    const float* b2   = (const float*)d_in[7];
    const float* Wc1  = (const float*)d_in[8];
    const float* bc1  = (const float*)d_in[9];
    const float* Wc2  = (const float*)d_in[10];
    const float* bc2  = (const float*)d_in[11];
    float* out = (float*)d_out;

    // workspace layout (16B-aligned sections; counts all multiples keep table 16B-aligned)
    float* Y2      = (float*)d_ws;                          // 3,200,000 f
    int*   binned  = (int*)(Y2 + (size_t)N_NODES * HID);    // 1,000,000
    int*   ssrc    = binned + N_EDGES;                      // 1,000,000
    int2*  nodeinfo = (int2*)(ssrc + N_EDGES);              // 100,000 int2
    int*   counts  = (int*)(nodeinfo + N_NODES);            // 245*391 = 95,795
    int*   offs    = counts + NBINBLK * NBUCK;              // 95,795
    int*   bbase   = offs + NBINBLK * NBUCK;                // 392
    int*   row_ptr = bbase + NBUCK + 1;                     // 100,001 (+1 pad)
    float* dinv    = (float*)(row_ptr + N_NODES + 2);       // 100,000
    float* table   = dinv + N_NODES;                        // 6,400
    float* pooled  = table + NUM_TYPES * HID;               // 8,192

    const int B = 256;
    const int gNode8 = (N_NODES * 8) / B;       // exact: 3125

    // CSR build via bucket binning (coalesced writes)
    k_binA<<<NBINBLK, B, 0, stream>>>(dst, counts);
    k_misc<<<3, 512, 0, stream>>>(counts, offs, bbase, emb, W1, table, pooled);
    k_binB<<<NBINBLK, B, 0, stream>>>(src, dst, offs, binned);
    k_csr<<<NBUCK, B, 0, stream>>>(binned, bbase, ids, ssrc, row_ptr, dinv, nodeinfo);

    // fused layer1 + W2 producer
    k_gather1<<<gNode8, B, 0, stream>>>(nodeinfo, table, row_ptr, ssrc, b1, W2,
                                        (float4*)Y2);
    // fused layer2 + pooling
    k_gather2<<<gNode8, B, 0, stream>>>((const float4*)Y2, row_ptr, ssrc, dinv, b2,
                                        batch, pooled);
    // head
    k_head<<<1, N_GRAPHS, 0, stream>>>(pooled, batch, Wc1, bc1, Wc2, bc2, out);
}

// Round 8
// 125.965 us; speedup vs baseline: 4.5300x; 1.0105x over previous
//
#include <hip/hip_runtime.h>
#include <hip/hip_fp16.h>
#include <math.h>

#define N_NODES   100000
#define N_EDGES   1000000
#define N_GRAPHS  256
#define NUM_TYPES 200
#define EMB       64
#define HID       32

#define BSHIFT    8
#define BSTRIDE   256                                   // nodes per bucket
#define NBUCK     ((N_NODES + BSTRIDE - 1) / BSTRIDE)   // 391
#define EPB       4096                                  // edges per bin block
#define NBINBLK   ((N_EDGES + EPB - 1) / EPB)           // 245
#define MAXBE     4096                                  // max edges per bucket (mean 2560)
#define SRCBITS   17                                    // 100000 < 2^17
#define SRCMASK   0x1FFFF

// ---------------- binning -> per-node CSR ----------------

__global__ __launch_bounds__(256) void k_binA(const int* __restrict__ dst,
                                              int* __restrict__ counts) {
    __shared__ int cnt[NBUCK];
    int tid = threadIdx.x, k = blockIdx.x;
    for (int b = tid; b < NBUCK; b += 256) cnt[b] = 0;
    __syncthreads();
    int base = k * EPB;
    int n = min(EPB, N_EDGES - base);
    for (int t = tid; t < n; t += 256) atomicAdd(&cnt[dst[base + t] >> BSHIFT], 1);
    __syncthreads();
    for (int b = tid; b < NBUCK; b += 256) counts[k * NBUCK + b] = cnt[b];
}

// block 0: scan -> offs/bbase; block 1: table = emb@W1; block 2: zero pooled
__global__ __launch_bounds__(512) void k_misc(const int* __restrict__ counts,
                                              int* __restrict__ offs,
                                              int* __restrict__ bbase,
                                              const float* __restrict__ emb,
                                              const float* __restrict__ W1,
                                              float* __restrict__ table,
                                              float* __restrict__ pooled) {
    int tid = threadIdx.x;
    if (blockIdx.x == 0) {
        __shared__ int sA[512], sB[512];
        int total = 0;
        if (tid < NBUCK)
            for (int k = 0; k < NBINBLK; ++k) total += counts[k * NBUCK + tid];
        sA[tid] = (tid < NBUCK) ? total : 0;
        __syncthreads();
        int* in = sA; int* out = sB;
        for (int off = 1; off < 512; off <<= 1) {
            out[tid] = in[tid] + (tid >= off ? in[tid - off] : 0);
            __syncthreads();
            int* tmp = in; in = out; out = tmp;
        }
        int excl = in[tid] - ((tid < NBUCK) ? total : 0);
        if (tid < NBUCK) {
            bbase[tid] = excl;
            int run = excl;
            for (int k = 0; k < NBINBLK; ++k) {
                offs[k * NBUCK + tid] = run;
                run += counts[k * NBUCK + tid];
            }
        }
        if (tid == 0) bbase[NBUCK] = N_EDGES;
    } else if (blockIdx.x == 1) {
        for (int t = tid; t < NUM_TYPES * HID; t += 512) {
            int ty = t / HID, j = t % HID;
            float s = 0.f;
            for (int k = 0; k < EMB; ++k) s = fmaf(emb[ty * EMB + k], W1[k * HID + j], s);
            table[t] = s;
        }
    } else {
        for (int t = tid; t < N_GRAPHS * HID; t += 512) pooled[t] = 0.f;
    }
}

// LDS counting-sort by bucket within each block; packed (dlow<<17)|src output
__global__ __launch_bounds__(256) void k_binB(const int* __restrict__ src,
                                              const int* __restrict__ dst,
                                              const int* __restrict__ offs,
                                              int* __restrict__ binned) {
    __shared__ int srcl[EPB];
    __shared__ int dstl[EPB];
    __shared__ unsigned short rank16[EPB];
    __shared__ unsigned short perm[EPB];
    __shared__ int cnt[NBUCK];
    __shared__ int loc[NBUCK];
    __shared__ int offsL[NBUCK];
    __shared__ int sA[512], sB[512];
    int tid = threadIdx.x, k = blockIdx.x;
    int base = k * EPB;
    int n = min(EPB, N_EDGES - base);
    for (int b = tid; b < NBUCK; b += 256) { cnt[b] = 0; offsL[b] = offs[k * NBUCK + b]; }
    __syncthreads();
    for (int t = tid; t < n; t += 256) {
        int s = src[base + t], d = dst[base + t];
        srcl[t] = s; dstl[t] = d;
        rank16[t] = (unsigned short)atomicAdd(&cnt[d >> BSHIFT], 1);
    }
    __syncthreads();
    for (int t = tid; t < 512; t += 256) sA[t] = (t < NBUCK) ? cnt[t] : 0;
    __syncthreads();
    int* in = sA; int* out = sB;
    for (int off = 1; off < 512; off <<= 1) {
        for (int t = tid; t < 512; t += 256)
            out[t] = in[t] + (t >= off ? in[t - off] : 0);
        __syncthreads();
        int* tmp = in; in = out; out = tmp;
    }
    for (int b = tid; b < NBUCK; b += 256) loc[b] = in[b] - cnt[b];
    __syncthreads();
    for (int t = tid; t < n; t += 256) {
        int b = dstl[t] >> BSHIFT;
        perm[loc[b] + rank16[t]] = (unsigned short)t;
    }
    __syncthreads();
    for (int t = tid; t < n; t += 256) {
        int e = perm[t];
        int d = dstl[e], b = d >> BSHIFT;
        int gpos = offsL[b] + (t - loc[b]);
        binned[gpos] = ((d & (BSTRIDE - 1)) << SRCBITS) | srcl[e];
    }
}

// one block per bucket: sort by node -> ssrc (coalesced), row_ptr, dinv, nodeinfo
__global__ __launch_bounds__(256) void k_csr(const int* __restrict__ binned,
                                             const int* __restrict__ bbase,
                                             const int* __restrict__ ids,
                                             int* __restrict__ ssrc,
                                             int* __restrict__ row_ptr,
                                             float* __restrict__ dinv,
                                             int2* __restrict__ nodeinfo) {
    __shared__ int pk[MAXBE];
    __shared__ unsigned char dl[MAXBE];
    __shared__ unsigned short rank16[MAXBE];
    __shared__ unsigned short perm[MAXBE];
    __shared__ int degL[BSTRIDE];
    __shared__ int loc[BSTRIDE];
    __shared__ int sA[BSTRIDE], sB[BSTRIDE];
    int tid = threadIdx.x, b = blockIdx.x;
    int e0 = bbase[b], e1 = bbase[b + 1];
    int n = min(e1 - e0, MAXBE);
    degL[tid] = 0;
    __syncthreads();
    for (int t = tid; t < n; t += 256) {
        int v = binned[e0 + t];
        pk[t] = v;
        int d = v >> SRCBITS;
        dl[t] = (unsigned char)d;
        rank16[t] = (unsigned short)atomicAdd(&degL[d], 1);
    }
    __syncthreads();
    sA[tid] = degL[tid];
    __syncthreads();
    int* in = sA; int* out = sB;
    for (int off = 1; off < 256; off <<= 1) {
        out[tid] = in[tid] + (tid >= off ? in[tid - off] : 0);
        __syncthreads();
        int* tmp = in; in = out; out = tmp;
    }
    loc[tid] = in[tid] - degL[tid];
    __syncthreads();
    for (int t = tid; t < n; t += 256)
        perm[loc[dl[t]] + rank16[t]] = (unsigned short)t;
    __syncthreads();
    for (int t = tid; t < n; t += 256)
        ssrc[e0 + t] = pk[perm[t]] & SRCMASK;
    int i = b * BSTRIDE + tid;
    if (i < N_NODES) {
        row_ptr[i] = e0 + loc[tid];
        float dv = rsqrtf((float)degL[tid] + 1.0f);
        dinv[i] = dv;
        nodeinfo[i] = make_int2(ids[i], __float_as_int(dv));
    }
    if (b == NBUCK - 1 && tid == 0) row_ptr[N_NODES] = N_EDGES;
}

// per-edge payload precompute: einfo[e] = (ids[src]<<16) | f16bits(dinv[src])
__global__ __launch_bounds__(256) void k_einfo(const int* __restrict__ ssrc,
                                               const int2* __restrict__ nodeinfo,
                                               unsigned int* __restrict__ einfo) {
    int e0 = (blockIdx.x * 256 + threadIdx.x) * 4;
    if (e0 >= N_EDGES) return;
    int4 s4 = *(const int4*)(ssrc + e0);
    int2 n0 = nodeinfo[s4.x], n1 = nodeinfo[s4.y];
    int2 n2 = nodeinfo[s4.z], n3 = nodeinfo[s4.w];
    uint4 r;
    r.x = ((unsigned)n0.x << 16) | __half_as_ushort(__float2half(__int_as_float(n0.y)));
    r.y = ((unsigned)n1.x << 16) | __half_as_ushort(__float2half(__int_as_float(n1.y)));
    r.z = ((unsigned)n2.x << 16) | __half_as_ushort(__float2half(__int_as_float(n2.y)));
    r.w = ((unsigned)n3.x << 16) | __half_as_ushort(__float2half(__int_as_float(n3.y)));
    *(uint4*)(einfo + e0) = r;
}

// ---------------- feature pipeline ----------------

// Layer 1 + layer-2 producer, fused; 8 lanes/node; sequential einfo reads only.
__global__ __launch_bounds__(256) void k_gather1(
        const int2* __restrict__ nodeinfo, const float* __restrict__ table,
        const int* __restrict__ row_ptr, const unsigned int* __restrict__ einfo,
        const float* __restrict__ b1, const float* __restrict__ W2,
        uint2* __restrict__ Y2h) {
    __shared__ float w[HID * HID];
    for (int k = threadIdx.x; k < HID * HID; k += 256) w[k] = W2[k];
    __syncthreads();

    int t = blockIdx.x * 256 + threadIdx.x;          // exact grid: 800000
    int i = t >> 3, p = t & 7;
    const float4* tab4 = (const float4*)table;

    int s0 = row_ptr[i], n = row_ptr[i + 1] - s0;
    int2 self = nodeinfo[i];
    float di = __int_as_float(self.y);
    float4 acc = tab4[self.x * 8 + p];               // self term
    acc.x *= di; acc.y *= di; acc.z *= di; acc.w *= di;

    for (int e = 0; e < n; e += 8) {
        unsigned int ei[8];
#pragma unroll
        for (int u = 0; u < 8; ++u) {
            int idx = e + u; idx = (idx > n - 1) ? n - 1 : idx;
            ei[u] = einfo[s0 + idx];
        }
#pragma unroll
        for (int u = 0; u < 8; ++u) {
            float ds = (e + u < n)
                ? __half2float(__ushort_as_half((unsigned short)(ei[u] & 0xFFFF))) : 0.f;
            float4 v = tab4[(ei[u] >> 16) * 8 + p];
            acc.x = fmaf(v.x, ds, acc.x);
            acc.y = fmaf(v.y, ds, acc.y);
            acc.z = fmaf(v.z, ds, acc.z);
            acc.w = fmaf(v.w, ds, acc.w);
        }
    }
    float4 bb = ((const float4*)b1)[p];
    float4 h;
    h.x = fmaxf(fmaf(di, acc.x, bb.x), 0.f);
    h.y = fmaxf(fmaf(di, acc.y, bb.y), 0.f);
    h.z = fmaxf(fmaf(di, acc.z, bb.z), 0.f);
    h.w = fmaxf(fmaf(di, acc.w, bb.w), 0.f);

    // out[4p+c] = sum_k h[k] * W2[k][4p+c] via intra-8-lane shuffles
    float o0 = 0.f, o1 = 0.f, o2 = 0.f, o3 = 0.f;
    const float4* w4 = (const float4*)w;
#pragma unroll
    for (int q = 0; q < 8; ++q) {
        float4 hq;
        hq.x = __shfl(h.x, q, 8);
        hq.y = __shfl(h.y, q, 8);
        hq.z = __shfl(h.z, q, 8);
        hq.w = __shfl(h.w, q, 8);
        float4 w0 = w4[(4 * q + 0) * 8 + p];
        float4 w1 = w4[(4 * q + 1) * 8 + p];
        float4 w2 = w4[(4 * q + 2) * 8 + p];
        float4 w3 = w4[(4 * q + 3) * 8 + p];
        o0 = fmaf(hq.x, w0.x, o0); o1 = fmaf(hq.x, w0.y, o1); o2 = fmaf(hq.x, w0.z, o2); o3 = fmaf(hq.x, w0.w, o3);
        o0 = fmaf(hq.y, w1.x, o0); o1 = fmaf(hq.y, w1.y, o1); o2 = fmaf(hq.y, w1.z, o2); o3 = fmaf(hq.y, w1.w, o3);
        o0 = fmaf(hq.z, w2.x, o0); o1 = fmaf(hq.z, w2.y, o1); o2 = fmaf(hq.z, w2.z, o2); o3 = fmaf(hq.z, w2.w, o3);
        o0 = fmaf(hq.w, w3.x, o0); o1 = fmaf(hq.w, w3.y, o1); o2 = fmaf(hq.w, w3.z, o2); o3 = fmaf(hq.w, w3.w, o3);
    }
    __half2 h01 = __halves2half2(__float2half(o0 * di), __float2half(o1 * di));
    __half2 h23 = __halves2half2(__float2half(o2 * di), __float2half(o3 * di));
    uint2 wv;
    wv.x = *(unsigned int*)&h01;
    wv.y = *(unsigned int*)&h23;
    Y2h[i * 8 + p] = wv;
}

// Layer 2 (f16 payload) + fused mean-pool partial sums; 8-deep pipelined.
__global__ __launch_bounds__(256) void k_gather2(
        const uint2* __restrict__ Y2h, const int* __restrict__ row_ptr,
        const int* __restrict__ ssrc, const float* __restrict__ dinv,
        const float* __restrict__ b2, const int* __restrict__ batch,
        float* __restrict__ pooled) {
    __shared__ float lp[32][HID];                    // per-block per-graph partials
    for (int k = threadIdx.x; k < 32 * HID; k += 256) ((float*)lp)[k] = 0.f;
    __syncthreads();

    int t = blockIdx.x * 256 + threadIdx.x;
    int i = t >> 3, p = t & 7;
    int i0 = (blockIdx.x * 256) >> 3;                // first node of block
    int gFirst = batch[i0];

    uint2 selfv = Y2h[i * 8 + p];                    // self term
    float2 sa = __half22float2(*(__half2*)&selfv.x);
    float2 sb = __half22float2(*(__half2*)&selfv.y);
    float4 acc = make_float4(sa.x, sa.y, sb.x, sb.y);

    int s0 = row_ptr[i], n = row_ptr[i + 1] - s0;
    for (int e = 0; e < n; e += 8) {
        int ss[8];
#pragma unroll
        for (int u = 0; u < 8; ++u) {
            int idx = e + u; idx = (idx > n - 1) ? n - 1 : idx;
            ss[u] = ssrc[s0 + idx];
        }
        uint2 v[8];
#pragma unroll
        for (int u = 0; u < 8; ++u) v[u] = Y2h[ss[u] * 8 + p];
#pragma unroll
        for (int u = 0; u < 8; ++u) {
            float wg = (e + u < n) ? 1.f : 0.f;
            float2 fa = __half22float2(*(__half2*)&v[u].x);
            float2 fb = __half22float2(*(__half2*)&v[u].y);
            acc.x = fmaf(fa.x, wg, acc.x);
            acc.y = fmaf(fa.y, wg, acc.y);
            acc.z = fmaf(fb.x, wg, acc.z);
            acc.w = fmaf(fb.y, wg, acc.w);
        }
    }
    float di = dinv[i];
    float4 bb = ((const float4*)b2)[p];
    float4 h;
    h.x = fmaxf(fmaf(di, acc.x, bb.x), 0.f);
    h.y = fmaxf(fmaf(di, acc.y, bb.y), 0.f);
    h.z = fmaxf(fmaf(di, acc.z, bb.z), 0.f);
    h.w = fmaxf(fmaf(di, acc.w, bb.w), 0.f);

    int gl = batch[i] - gFirst;                      // 0..31 within block
    atomicAdd(&lp[gl][p * 4 + 0], h.x);
    atomicAdd(&lp[gl][p * 4 + 1], h.y);
    atomicAdd(&lp[gl][p * 4 + 2], h.z);
    atomicAdd(&lp[gl][p * 4 + 3], h.w);
    __syncthreads();

    int gLast = batch[i0 + 31];
    int ng = gLast - gFirst + 1;
    for (int k = threadIdx.x; k < ng * HID; k += 256) {
        float v = lp[k / HID][k % HID];
        if (v != 0.f) atomicAdd(&pooled[(gFirst + k / HID) * HID + (k % HID)], v);
    }
}

// head: mean (counts via binary search) -> relu(@Wc1+bc1) -> sigmoid(@Wc2+bc2)
__global__ void k_head(const float* __restrict__ pooled, const int* __restrict__ batch,
                       const float* __restrict__ Wc1, const float* __restrict__ bc1,
                       const float* __restrict__ Wc2, const float* __restrict__ bc2,
                       float* __restrict__ out) {
    int g = blockIdx.x * blockDim.x + threadIdx.x;
    if (g >= N_GRAPHS) return;
    int lo = 0, hi = N_NODES;
    while (lo < hi) { int mid = (lo + hi) >> 1; if (batch[mid] < g) lo = mid + 1; else hi = mid; }
    int start = lo;
    hi = N_NODES;
    while (lo < hi) { int mid = (lo + hi) >> 1; if (batch[mid] < g + 1) lo = mid + 1; else hi = mid; }
    int end = lo;
    float inv = 1.0f / fmaxf((float)(end - start), 1.0f);
    float m[HID];
    for (int j = 0; j < HID; ++j) m[j] = pooled[g * HID + j] * inv;
    float hc[16];
    for (int j = 0; j < 16; ++j) {
        float s = bc1[j];
        for (int k = 0; k < HID; ++k) s = fmaf(m[k], Wc1[k * 16 + j], s);
        hc[j] = fmaxf(s, 0.f);
    }
    float s = bc2[0];
    for (int k = 0; k < 16; ++k) s = fmaf(hc[k], Wc2[k], s);
    out[g] = 1.0f / (1.0f + expf(-s));
}

// ---------------- launch ----------------

extern "C" void kernel_launch(void* const* d_in, const int* in_sizes, int n_in,
                              void* d_out, int out_size, void* d_ws, size_t ws_size,
                              hipStream_t stream) {
    const int*   ids  = (const int*)d_in[0];
    const int*   src  = (const int*)d_in[1];
    const int*   dst  = ((const int*)d_in[1]) + N_EDGES;
    const int*   batch = (const int*)d_in[2];
    const float* emb  = (const float*)d_in[3];
    const float* W1   = (const float*)d_in[4];
    const float* b1   = (const float*)d_in[5];
    const float* W2   = (const float*)d_in[6];
    const float* b2   = (const float*)d_in[7];
    const float* Wc1  = (const float*)d_in[8];
    const float* bc1  = (const float*)d_in[9];
    const float* Wc2  = (const float*)d_in[10];
    const float* bc2  = (const float*)d_in[11];
    float* out = (float*)d_out;

    // workspace layout (Y2h first for 16B alignment; rest 4B types)
    uint2* Y2h     = (uint2*)d_ws;                          // 800,000 uint2 (6.4MB)
    int*   binned  = (int*)(Y2h + (size_t)N_NODES * 8);     // 1,000,000
    int*   ssrc    = binned + N_EDGES;                      // 1,000,000
    unsigned int* einfo = (unsigned int*)(ssrc + N_EDGES);  // 1,000,000
    int2*  nodeinfo = (int2*)(einfo + N_EDGES);             // 100,000 int2
    int*   counts  = (int*)(nodeinfo + N_NODES);            // 95,795
    int*   offs    = counts + NBINBLK * NBUCK;              // 95,795
    int*   bbase   = offs + NBINBLK * NBUCK;                // 392
    int*   row_ptr = bbase + NBUCK + 1;                     // 100,001 (+pad)
    float* dinv    = (float*)(row_ptr + N_NODES + 2);       // 100,000
    float* table   = dinv + N_NODES;                        // 6,400
    float* pooled  = table + NUM_TYPES * HID;               // 8,192

    const int B = 256;
    const int gNode8 = (N_NODES * 8) / B;       // exact: 3125

    // CSR build via bucket binning (coalesced writes)
    k_binA<<<NBINBLK, B, 0, stream>>>(dst, counts);
    k_misc<<<3, 512, 0, stream>>>(counts, offs, bbase, emb, W1, table, pooled);
    k_binB<<<NBINBLK, B, 0, stream>>>(src, dst, offs, binned);
    k_csr<<<NBUCK, B, 0, stream>>>(binned, bbase, ids, ssrc, row_ptr, dinv, nodeinfo);
    k_einfo<<<(N_EDGES / 4 + B - 1) / B, B, 0, stream>>>(ssrc, nodeinfo, einfo);

    // fused layer1 + W2 producer (sequential einfo reads)
    k_gather1<<<gNode8, B, 0, stream>>>(nodeinfo, table, row_ptr, einfo, b1, W2, Y2h);
    // fused layer2 + pooling (f16 payload)
    k_gather2<<<gNode8, B, 0, stream>>>((const uint2*)Y2h, row_ptr, ssrc, dinv, b2,
                                        batch, pooled);
    // head
    k_head<<<1, N_GRAPHS, 0, stream>>>(pooled, batch, Wc1, bc1, Wc2, bc2, out);
}